// Round 7
// baseline (10.771 us; speedup 1.0000x reference)
//
#include <hip/hip_runtime.h>
#include <hip/hip_bf16.h>
#include <math.h>

// DescriptorMatcher, fully fused single dispatch. b=1, c=64, N=1024.
//   out[i,j,o] = sum_c v1[i,c]*v2[j,c]*W[o,c] + bias[o]
//   onorm[i,j] = sqrt(s1[i] + s2[j] - 2*dot(i,j)*r1[i]*r2[j])
// One 64-thread (1-wave) block computes a 16x16 output tile.
// Precision scheme (threshold 0.13, measured absmax 0.03125):
//   - plain dot: 2-term split  Ah*(Bh+Bl); W-variants: hi-only. 8 MFMAs.
// SWAPPED operand order vs R6: mfma(v2frag, v1frag) -> lane owns
// (i = i0+m fixed, j = j0+kg*4+p consecutive) => out/onorm stores become
// 3 contiguous nontemporal dwordx4 per lane (was 8 scattered stores), and
// s1/r1 are lane-local (no shuffle).
// 4096 blocks = 4 waves/SIMD, no LDS, no barriers, single dispatch.

#define CDIM 64
#define EPSN 1e-6f

typedef float        f4  __attribute__((ext_vector_type(4)));
typedef short        s8v __attribute__((ext_vector_type(8)));
typedef unsigned int u32;

__device__ __forceinline__ short bf16_hi(float x) {
    return (short)__bfloat16_as_ushort(__float2bfloat16(x));
}

__global__ __launch_bounds__(64, 4)
void fused_kernel(const float* __restrict__ g1, const float* __restrict__ g2,
                  const float* __restrict__ W, const float* __restrict__ bias,
                  float* __restrict__ out, float* __restrict__ onorm, int N) {
    const int l  = threadIdx.x;
    const int m  = l & 15;       // v1-row i0+m, v2-col j0+m (gather slots)
    const int kg = l >> 4;       // k-group
    const int j0 = blockIdx.x * 16;
    const int i0 = blockIdx.y * 16;
    const int cb = kg * 8;       // k-slot base within each 32-wide k-half

    // ---- raw fp32 gathers (inputs 512 KB -> L2-resident)
    float xa[2][8], xb[2][8];    // [kh][q]; A row = i0+m, B col = j0+m
    #pragma unroll
    for (int kh = 0; kh < 2; ++kh)
        #pragma unroll
        for (int q = 0; q < 8; ++q) {
            const size_t coff = (size_t)(kh * 32 + cb + q) * N;
            xa[kh][q] = g1[coff + (i0 + m)];
            xb[kh][q] = g2[coff + (j0 + m)];
        }

    float wv[2][2][8];   // W[o][kh*32+cb+q]
    #pragma unroll
    for (int o = 0; o < 2; ++o)
        #pragma unroll
        for (int kh = 0; kh < 2; ++kh) {
            *(f4*)&wv[o][kh][0] = *(const f4*)&W[o * CDIM + kh * 32 + cb];
            *(f4*)&wv[o][kh][4] = *(const f4*)&W[o * CDIM + kh * 32 + cb + 4];
        }

    // ---- norm sums (fp32 exact): lane partial (16 c's) + butterfly over kg
    float ss1 = 0.f, ss2 = 0.f;
    #pragma unroll
    for (int kh = 0; kh < 2; ++kh)
        #pragma unroll
        for (int q = 0; q < 8; ++q) {
            ss1 = fmaf(xa[kh][q], xa[kh][q], ss1);
            ss2 = fmaf(xb[kh][q], xb[kh][q], ss2);
        }
    ss1 += __shfl_xor(ss1, 16);  ss1 += __shfl_xor(ss1, 32);
    ss2 += __shfl_xor(ss2, 16);  ss2 += __shfl_xor(ss2, 32);

    const float r1  = 1.0f / (EPSN + sqrtf(ss1));   // for row i = i0+m (local!)
    const float s1e = ss1 * r1 * r1;
    const float r2  = 1.0f / (EPSN + sqrtf(ss2));   // for col j = j0+m
    const float s2e = ss2 * r2 * r2;
    const float r2m = r2 * -2.0f;

    // ---- bf16 fragments in-register (v1: hi only; v2: hi+lo; v2*w: hi only)
    s8v Ah[2], Bh[2], Bl[2], Bw0[2], Bw1[2];
    #pragma unroll
    for (int kh = 0; kh < 2; ++kh)
        #pragma unroll
        for (int q = 0; q < 8; ++q) {
            Ah[kh][q] = bf16_hi(xa[kh][q]);
            float x = xb[kh][q];
            short h = bf16_hi(x);
            Bh[kh][q] = h;
            Bl[kh][q] = bf16_hi(x - __bfloat162float(__ushort_as_bfloat16((unsigned short)h)));
            Bw0[kh][q] = bf16_hi(x * wv[0][kh][q]);
            Bw1[kh][q] = bf16_hi(x * wv[1][kh][q]);
        }

    const float b0 = bias[0], b1 = bias[1];
    f4 acc[3];                   // [variant: dot, out0, out1]
    acc[0] = (f4){0.f, 0.f, 0.f, 0.f};
    acc[1] = (f4){b0, b0, b0, b0};
    acc[2] = (f4){b1, b1, b1, b1};

    // ---- 8 MFMAs, v2-fragment as first operand:
    //      D[r=j-slot][c=i-slot], lane: c = m, r = kg*4 + p
    #pragma unroll
    for (int kh = 0; kh < 2; ++kh) {
        acc[0] = __builtin_amdgcn_mfma_f32_16x16x32_bf16(Bh[kh],  Ah[kh], acc[0], 0, 0, 0);
        acc[0] = __builtin_amdgcn_mfma_f32_16x16x32_bf16(Bl[kh],  Ah[kh], acc[0], 0, 0, 0);
        acc[1] = __builtin_amdgcn_mfma_f32_16x16x32_bf16(Bw0[kh], Ah[kh], acc[1], 0, 0, 0);
        acc[2] = __builtin_amdgcn_mfma_f32_16x16x32_bf16(Bw1[kh], Ah[kh], acc[2], 0, 0, 0);
    }

    // ---- epilogue: lane owns i = i0+m, j = j0 + kg*4 + p (p = 0..3)
    //      s1/r1 are lane-local; s2/r2 pulled from lane (kg*4+p) via shfl
    f4 dn, o0, o1;
    #pragma unroll
    for (int p = 0; p < 4; ++p) {
        const int rsel = kg * 4 + p;          // lane holding col j0+rsel scalars
        const float s2r = __shfl(s2e, rsel);
        const float r2r = __shfl(r2m, rsel);
        const float dd  = acc[0][p];
        const float d2  = fmaf(dd * r1, r2r, s1e + s2r);
        dn[p] = sqrtf(fmaxf(d2, 0.0f));
    }
    o0[0] = acc[1][0]; o0[1] = acc[2][0]; o0[2] = acc[1][1]; o0[3] = acc[2][1];
    o1[0] = acc[1][2]; o1[1] = acc[2][2]; o1[2] = acc[1][3]; o1[3] = acc[2][3];

    const size_t pbase = (size_t)(i0 + m) * N + j0 + kg * 4;  // first pair idx
    __builtin_nontemporal_store(o0, (f4*)&out[pbase * 2]);
    __builtin_nontemporal_store(o1, (f4*)&out[pbase * 2 + 4]);
    __builtin_nontemporal_store(dn, (f4*)&onorm[pbase]);
}

extern "C" void kernel_launch(void* const* d_in, const int* in_sizes, int n_in,
                              void* d_out, int out_size, void* d_ws, size_t ws_size,
                              hipStream_t stream) {
    const float* g1   = (const float*)d_in[0];
    const float* g2   = (const float*)d_in[1];
    const float* W    = (const float*)d_in[2];
    const float* bias = (const float*)d_in[3];

    const int N = in_sizes[0] / CDIM;              // 1024
    float* out   = (float*)d_out;                  // [N*N, 2]
    float* onorm = out + (size_t)2 * N * N;        // [N, N]

    dim3 grid(N / 16, N / 16);                     // 64 x 64 = 4096 blocks
    fused_kernel<<<grid, 64, 0, stream>>>(g1, g2, W, bias, out, onorm, N);
}

// Round 8
// 10.526 us; speedup vs baseline: 1.0233x; 1.0233x over previous
//
#include <hip/hip_runtime.h>
#include <hip/hip_bf16.h>
#include <math.h>

// DescriptorMatcher, fully fused single dispatch. b=1, c=64, N=1024.
//   out[i,j,o] = sum_c v1[i,c]*v2[j,c]*W[o,c] + bias[o]
//   onorm[i,j] = sqrt(s1[i] + s2[j] - 2*dot(i,j)*r1[i]*r2[j])
// One 64-thread (1-wave) block computes a 16x16 output tile.
// Precision scheme (threshold 0.13, measured absmax 0.03125):
//   - plain dot: 2-term split  Ah*(Bh+Bl)  -> dot err damped by 2*r1*r2 in d^2.
//   - W-variants: hi-only Ah*Bh -> |W|~0.125-damped err well under threshold.
//   => 8 MFMAs total, no A-lo fragments.
// Non-temporal stores: outputs are streamed (12.6 MB), never re-read; wave's
// 64 lanes cover full cache lines collectively (R7 showed contiguous-per-lane
// stores gain nothing and cost shuffles).
// 4096 blocks = 4 waves/SIMD, no LDS, no barriers, single dispatch.
// Best measured: 10.52 us (≈8 us fixed replay overhead + ~2.3 us write floor).

#define CDIM 64
#define EPSN 1e-6f

typedef float        f4  __attribute__((ext_vector_type(4)));
typedef float        f2  __attribute__((ext_vector_type(2)));
typedef short        s8v __attribute__((ext_vector_type(8)));
typedef unsigned int u32;

__device__ __forceinline__ short bf16_hi(float x) {
    return (short)__bfloat16_as_ushort(__float2bfloat16(x));
}

__global__ __launch_bounds__(64, 4)
void fused_kernel(const float* __restrict__ g1, const float* __restrict__ g2,
                  const float* __restrict__ W, const float* __restrict__ bias,
                  float* __restrict__ out, float* __restrict__ onorm, int N) {
    const int l  = threadIdx.x;
    const int m  = l & 15;       // A-row / B-col / C-col within tile
    const int kg = l >> 4;       // k-group
    const int j0 = blockIdx.x * 16;
    const int i0 = blockIdx.y * 16;
    const int cb = kg * 8;       // k-slot base within each 32-wide k-half

    // ---- raw fp32 gathers (inputs 512 KB -> L2-resident)
    float xa[2][8], xb[2][8];    // [kh][q]; A row = i0+m, B col = j0+m
    #pragma unroll
    for (int kh = 0; kh < 2; ++kh)
        #pragma unroll
        for (int q = 0; q < 8; ++q) {
            const size_t coff = (size_t)(kh * 32 + cb + q) * N;
            xa[kh][q] = g1[coff + (i0 + m)];
            xb[kh][q] = g2[coff + (j0 + m)];
        }

    float wv[2][2][8];   // W[o][kh*32+cb+q]
    #pragma unroll
    for (int o = 0; o < 2; ++o)
        #pragma unroll
        for (int kh = 0; kh < 2; ++kh) {
            *(f4*)&wv[o][kh][0] = *(const f4*)&W[o * CDIM + kh * 32 + cb];
            *(f4*)&wv[o][kh][4] = *(const f4*)&W[o * CDIM + kh * 32 + cb + 4];
        }

    // ---- norm sums (fp32 exact): lane partial (16 c's) + butterfly over kg
    float ss1 = 0.f, ss2 = 0.f;
    #pragma unroll
    for (int kh = 0; kh < 2; ++kh)
        #pragma unroll
        for (int q = 0; q < 8; ++q) {
            ss1 = fmaf(xa[kh][q], xa[kh][q], ss1);
            ss2 = fmaf(xb[kh][q], xb[kh][q], ss2);
        }
    ss1 += __shfl_xor(ss1, 16);  ss1 += __shfl_xor(ss1, 32);
    ss2 += __shfl_xor(ss2, 16);  ss2 += __shfl_xor(ss2, 32);

    const float r1  = 1.0f / (EPSN + sqrtf(ss1));
    const float s1e = ss1 * r1 * r1;
    const float r2  = 1.0f / (EPSN + sqrtf(ss2));
    const float s2e = ss2 * r2 * r2;
    const float r2m = r2 * -2.0f;

    // ---- bf16 fragments in-register (A: hi only; B: hi+lo; Bw0/Bw1: hi only)
    s8v Ah[2], Bh[2], Bl[2], Bw0[2], Bw1[2];
    #pragma unroll
    for (int kh = 0; kh < 2; ++kh)
        #pragma unroll
        for (int q = 0; q < 8; ++q) {
            Ah[kh][q] = bf16_hi(xa[kh][q]);
            float x = xb[kh][q];
            short h = bf16_hi(x);
            Bh[kh][q] = h;
            Bl[kh][q] = bf16_hi(x - __bfloat162float(__ushort_as_bfloat16((unsigned short)h)));
            Bw0[kh][q] = bf16_hi(x * wv[0][kh][q]);
            Bw1[kh][q] = bf16_hi(x * wv[1][kh][q]);
        }

    const float b0 = bias[0], b1 = bias[1];
    f4 acc[3];                   // [variant: dot, out0, out1]
    acc[0] = (f4){0.f, 0.f, 0.f, 0.f};
    acc[1] = (f4){b0, b0, b0, b0};
    acc[2] = (f4){b1, b1, b1, b1};

    // ---- 8 MFMAs
    #pragma unroll
    for (int kh = 0; kh < 2; ++kh) {
        acc[0] = __builtin_amdgcn_mfma_f32_16x16x32_bf16(Ah[kh], Bh[kh],  acc[0], 0, 0, 0);
        acc[0] = __builtin_amdgcn_mfma_f32_16x16x32_bf16(Ah[kh], Bl[kh],  acc[0], 0, 0, 0);
        acc[1] = __builtin_amdgcn_mfma_f32_16x16x32_bf16(Ah[kh], Bw0[kh], acc[1], 0, 0, 0);
        acc[2] = __builtin_amdgcn_mfma_f32_16x16x32_bf16(Ah[kh], Bw1[kh], acc[2], 0, 0, 0);
    }

    // ---- epilogue: C layout col = m, row = kg*4 + p; row scalars via shfl
    #pragma unroll
    for (int p = 0; p < 4; ++p) {
        const int rsel = kg * 4 + p;           // lane holding this row's scalars
        const float s1r = __shfl(s1e, rsel);
        const float r1r = __shfl(r1, rsel);
        const int row = i0 + rsel;
        const float dd = acc[0][p];
        const float d2 = fmaf(dd * r1r, r2m, s1r + s2e);
        const float dn = sqrtf(fmaxf(d2, 0.0f));
        const size_t off = (size_t)row * N + (j0 + m);
        f2 o; o[0] = acc[1][p]; o[1] = acc[2][p];
        __builtin_nontemporal_store(o,  (f2*)&out[off * 2]);
        __builtin_nontemporal_store(dn, &onorm[off]);
    }
}

extern "C" void kernel_launch(void* const* d_in, const int* in_sizes, int n_in,
                              void* d_out, int out_size, void* d_ws, size_t ws_size,
                              hipStream_t stream) {
    const float* g1   = (const float*)d_in[0];
    const float* g2   = (const float*)d_in[1];
    const float* W    = (const float*)d_in[2];
    const float* bias = (const float*)d_in[3];

    const int N = in_sizes[0] / CDIM;              // 1024
    float* out   = (float*)d_out;                  // [N*N, 2]
    float* onorm = out + (size_t)2 * N * N;        // [N, N]

    dim3 grid(N / 16, N / 16);                     // 64 x 64 = 4096 blocks
    fused_kernel<<<grid, 64, 0, stream>>>(g1, g2, W, bias, out, onorm, N);
}